// Round 1
// baseline (1629.300 us; speedup 1.0000x reference)
//
#include <hip/hip_runtime.h>

#define NB 32
#define NR 16384
#define NF 256
#define NH 16
#define TOT (NB*NR)

// ---------------- Kernel 1: fused LN1 -> W1 -> ReLU -> LN2 -> W2 scores ----
// One row per 64-lane wave. LN affines folded:
//   pre_h = rstd*(dot(x,W1g[:,h]) - mu*u_h) + c_h,  W1g = g1*W1, u=sum_f W1g,
//   c_h = sum_f b1ln*W1 + b1
//   score = rstd2*(dot(h,g2*W2) - mu2*U2) + C2
__global__ __launch_bounds__(256) void k_scores(
    const float* __restrict__ table,
    const float* __restrict__ ln1_g, const float* __restrict__ ln1_b,
    const float* __restrict__ W1, const float* __restrict__ b1,
    const float* __restrict__ ln2_g, const float* __restrict__ ln2_b,
    const float* __restrict__ W2, const float* __restrict__ b2,
    float* __restrict__ scores)
{
    const int lane = threadIdx.x & 63;
    const int gw = (blockIdx.x * blockDim.x + threadIdx.x) >> 6;
    const int nw = (gridDim.x * blockDim.x) >> 6;

    float w1g[4][16];
    float up[16], cp[16];
    #pragma unroll
    for (int h = 0; h < 16; ++h) { up[h] = 0.f; cp[h] = 0.f; }
    #pragma unroll
    for (int r = 0; r < 4; ++r) {
        const int f = 4*lane + r;
        const float g  = ln1_g[f];
        const float bb = ln1_b[f];
        #pragma unroll
        for (int q = 0; q < 4; ++q) {
            float4 w = *(const float4*)(W1 + f*16 + 4*q);
            float wv[4] = {w.x, w.y, w.z, w.w};
            #pragma unroll
            for (int j = 0; j < 4; ++j) {
                int h = 4*q + j;
                cp[h] += bb * wv[j];
                float wg = g * wv[j];
                w1g[r][h] = wg;
                up[h] += wg;
            }
        }
    }
    #pragma unroll
    for (int m = 32; m >= 1; m >>= 1) {
        #pragma unroll
        for (int h = 0; h < 16; ++h) {
            up[h] += __shfl_xor(up[h], m, 64);
            cp[h] += __shfl_xor(cp[h], m, 64);
        }
    }
    #pragma unroll
    for (int h = 0; h < 16; ++h) cp[h] += b1[h];

    float g2w2[16];
    float U2 = 0.f, C2 = b2[0];
    #pragma unroll
    for (int h = 0; h < 16; ++h) {
        float w2v = W2[h];
        g2w2[h] = ln2_g[h] * w2v;
        U2 += g2w2[h];
        C2 += ln2_b[h] * w2v;
    }

    for (int row = gw; row < TOT; row += nw) {
        float4 x4 = *(const float4*)(table + (size_t)row*NF + 4*lane);
        float xs[4] = {x4.x, x4.y, x4.z, x4.w};
        float sum = 0.f, ssq = 0.f;
        float dx[16];
        #pragma unroll
        for (int h = 0; h < 16; ++h) dx[h] = 0.f;
        #pragma unroll
        for (int r = 0; r < 4; ++r) {
            sum += xs[r];
            ssq += xs[r]*xs[r];
            #pragma unroll
            for (int h = 0; h < 16; ++h) dx[h] += xs[r]*w1g[r][h];
        }
        #pragma unroll
        for (int m = 32; m >= 1; m >>= 1) {
            sum += __shfl_xor(sum, m, 64);
            ssq += __shfl_xor(ssq, m, 64);
            #pragma unroll
            for (int h = 0; h < 16; ++h) dx[h] += __shfl_xor(dx[h], m, 64);
        }
        float mu   = sum * (1.f/NF);
        float var  = ssq * (1.f/NF) - mu*mu;
        float rstd = rsqrtf(var + 1e-5f);
        float s2 = 0.f, q2 = 0.f, dh = 0.f;
        #pragma unroll
        for (int h = 0; h < 16; ++h) {
            float hv = rstd * (dx[h] - mu*up[h]) + cp[h];
            hv = fmaxf(hv, 0.f);
            s2 += hv; q2 += hv*hv; dh += hv * g2w2[h];
        }
        float mu2   = s2 * (1.f/NH);
        float var2  = q2 * (1.f/NH) - mu2*mu2;
        float rstd2 = rsqrtf(var2 + 1e-5f);
        float sc = rstd2 * (dh - mu2*U2) + C2;
        if (lane == 0) scores[row] = sc;
    }
}

// ---------------- Kernel 2: per-batch bitonic sort (desc val, ties idx desc)
__global__ __launch_bounds__(1024) void k_sort(
    const float* __restrict__ scores, float* __restrict__ sval, int* __restrict__ sidx)
{
    __shared__ float v[NR];
    __shared__ int  ix[NR];
    const int b = blockIdx.x;
    const float* s = scores + (size_t)b*NR;
    for (int i = threadIdx.x; i < NR; i += 1024) { v[i] = s[i]; ix[i] = i; }
    __syncthreads();
    for (int k = 2; k <= NR; k <<= 1) {
        for (int j = k >> 1; j > 0; j >>= 1) {
            for (int t = threadIdx.x; t < NR/2; t += 1024) {
                int i = ((t & ~(j-1)) << 1) | (t & (j-1));
                int l = i | j;
                float va = v[i], vb = v[l];
                int ia = ix[i], ib = ix[l];
                // target order: before(p,q) = p.v>q.v || (p.v==q.v && p.i>q.i)
                bool beforeBA = (vb > va) || (vb == va && ib > ia);
                bool up = ((i & k) == 0);
                if (beforeBA == up) {
                    v[i] = vb; v[l] = va;
                    ix[i] = ib; ix[l] = ia;
                }
            }
            __syncthreads();
        }
    }
    for (int i = threadIdx.x; i < NR; i += 1024) {
        sval[(size_t)b*NR + i] = v[i];
        sidx[(size_t)b*NR + i] = ix[i];
    }
}

// ---------------- Kernel 3: isotonic via least-concave-majorant of cumsum ---
__device__ __forceinline__ double Sval_at(const double* S, int k) {
    return (k == 0) ? 0.0 : S[k-1];
}

__global__ __launch_bounds__(1024) void k_pava(
    const float* __restrict__ sval, const int* __restrict__ sidx,
    const int* __restrict__ capp,
    int* __restrict__ Hbuf, int* __restrict__ counts,
    float* __restrict__ out_soft, float* __restrict__ out_bins)
{
    __shared__ double S[NR];      // S[i] = sum_{j<=i} y_j  (math S_{i+1}), 128 KiB
    __shared__ double aux[2048];  // scan ping-pong, 16 KiB
    const int b = blockIdx.x;
    const int tid = threadIdx.x;
    const float* sv = sval + (size_t)b*NR;
    const int*   si = sidx + (size_t)b*NR;
    int* H   = Hbuf   + (size_t)b*NR;
    int* cnt = counts + (size_t)b*1024;

    const float mx = sv[0];
    const float mn = sv[NR-1];
    const float scale = 10000.0f / (mx - mn);   // *100 (minmax) /0.01 (reg)

    // 1) per-thread 16-element local inclusive scan of y = s - w  (f64)
    double loc[16];
    double acc = 0.0;
    const int base = tid * 16;
    #pragma unroll
    for (int r = 0; r < 16; ++r) {
        int i = base + r;
        float s_i = (sv[i] - mn) * scale;
        double y = (double)s_i - (double)(NR - i);   // w_i = n - i
        acc += y;
        loc[r] = acc;
    }
    aux[tid] = acc;
    __syncthreads();
    // 2) Hillis-Steele over 1024 thread totals
    int src = 0;
    for (int d = 1; d < 1024; d <<= 1) {
        double t = aux[src*1024 + tid];
        if (tid >= d) t += aux[src*1024 + tid - d];
        aux[(src^1)*1024 + tid] = t;
        src ^= 1;
        __syncthreads();
    }
    double excl = aux[src*1024 + tid] - acc;
    #pragma unroll
    for (int r = 0; r < 16; ++r) S[base + r] = excl + loc[r];
    __syncthreads();

    // 3) level-0 chunk upper hulls: thread t handles points k = 16t..16t+15
    {
        int out = 0;
        const int hb = base;
        #pragma unroll 1
        for (int r = 0; r < 16; ++r) {
            int k = base + r;
            double xk = (double)k, yk = Sval_at(S, k);
            while (out >= 2) {
                int kb = H[hb + out - 1], ka = H[hb + out - 2];
                double xa = (double)ka, ya = Sval_at(S, ka);
                double xb = (double)kb, yb = Sval_at(S, kb);
                if ((xb - xa)*(yk - ya) - (yb - ya)*(xk - xa) >= 0.0) --out;
                else break;
            }
            H[hb + out++] = k;
        }
        cnt[tid] = out;
    }

    // 4) pairwise Graham merges, 10 levels (in-place safe: write pos <= read pos)
    for (int lev = 0; lev < 10; ++lev) {
        __syncthreads();
        int pairs = 512 >> lev;
        if (tid < pairs) {
            int Wd = 16 << lev;
            int lbase = tid * 2 * Wd;
            int rbase = lbase + Wd;
            int cl = cnt[(2*tid)   << lev];
            int cr = cnt[(2*tid+1) << lev];
            int out = 0;
            #pragma unroll 1
            for (int p = 0; p < cl + cr; ++p) {
                int k = (p < cl) ? H[lbase + p] : H[rbase + (p - cl)];
                double xk = (double)k, yk = Sval_at(S, k);
                while (out >= 2) {
                    int kb = H[lbase + out - 1], ka = H[lbase + out - 2];
                    double xa = (double)ka, ya = Sval_at(S, ka);
                    double xb = (double)kb, yb = Sval_at(S, kb);
                    if ((xb - xa)*(yk - ya) - (yb - ya)*(xk - xa) >= 0.0) --out;
                    else break;
                }
                H[lbase + out++] = k;
            }
            cnt[(2*tid) << lev] = out;
        }
    }
    __syncthreads();
    // 5) append rightmost point k = NR
    if (tid == 0) {
        int out = cnt[0];
        double xk = (double)NR, yk = S[NR-1];
        while (out >= 2) {
            int kb = H[out - 1], ka = H[out - 2];
            double xa = (double)ka, ya = Sval_at(S, ka);
            double xb = (double)kb, yb = Sval_at(S, kb);
            if ((xb - xa)*(yk - ya) - (yb - ya)*(xk - xa) >= 0.0) --out;
            else break;
        }
        H[out++] = NR;
        cnt[0] = out;
    }
    __syncthreads();

    // 6) slopes -> dual -> primal, scatter outputs; bins from hard rank
    const int m = cnt[0];
    const int cap = capp[0];
    for (int i = tid; i < NR; i += 1024) {
        int lo = 0, hi = m - 1;   // H[0]=0 <= i < NR = H[m-1]
        while (hi - lo > 1) {
            int mid = (lo + hi) >> 1;
            if (H[mid] <= i) lo = mid; else hi = mid;
        }
        int ka = H[lo], kb = H[hi];
        double slope = (Sval_at(S, kb) - Sval_at(S, ka)) / (double)(kb - ka);
        float s_i = (sv[i] - mn) * scale;
        float primal = (float)((double)s_i - slope);
        int idx = si[i];
        out_soft[(size_t)b*NR + idx] = primal;
        int rank = (NR - 1) - i;                      // ascending hard rank
        out_bins[(size_t)b*NR + idx] = (float)(rank / cap + 1);
    }
}

extern "C" void kernel_launch(void* const* d_in, const int* in_sizes, int n_in,
                              void* d_out, int out_size, void* d_ws, size_t ws_size,
                              hipStream_t stream)
{
    const float* table = (const float*)d_in[0];
    const float* ln1_g = (const float*)d_in[1];
    const float* ln1_b = (const float*)d_in[2];
    const float* W1    = (const float*)d_in[3];
    const float* b1    = (const float*)d_in[4];
    const float* ln2_g = (const float*)d_in[5];
    const float* ln2_b = (const float*)d_in[6];
    const float* W2    = (const float*)d_in[7];
    const float* b2    = (const float*)d_in[8];
    const int*   cap   = (const int*)d_in[9];

    float* scores = (float*)d_ws;            // TOT f32
    float* sval   = scores + TOT;            // TOT f32
    int*   sidx   = (int*)(sval + TOT);      // TOT i32
    int*   Hbuf   = sidx + TOT;              // TOT i32
    int*   counts = Hbuf + TOT;              // NB*1024 i32

    float* out_soft = (float*)d_out;
    float* out_bins = ((float*)d_out) + TOT;

    k_scores<<<4096, 256, 0, stream>>>(table, ln1_g, ln1_b, W1, b1,
                                       ln2_g, ln2_b, W2, b2, scores);
    k_sort<<<NB, 1024, 0, stream>>>(scores, sval, sidx);
    k_pava<<<NB, 1024, 0, stream>>>(sval, sidx, cap, Hbuf, counts,
                                    out_soft, out_bins);
}

// Round 2
// 1166.860 us; speedup vs baseline: 1.3963x; 1.3963x over previous
//
#include <hip/hip_runtime.h>

#define NB 32
#define NR 16384
#define NF 256
#define NH 16
#define TOT (NB*NR)

typedef unsigned long long u64;

// float <-> order-preserving u32 (ascending uint == ascending float)
__device__ __forceinline__ unsigned int f2u(float f) {
    unsigned int u = __float_as_uint(f);
    return (u & 0x80000000u) ? ~u : (u | 0x80000000u);
}
__device__ __forceinline__ float u2f(unsigned int s) {
    unsigned int u = (s & 0x80000000u) ? (s ^ 0x80000000u) : ~s;
    return __uint_as_float(u);
}

// reduce-scatter 16 values over lanes: returns full sum of v[h] where
// h = (lane>>2)&15; all 4 replicas (bits 0,1) hold the same result.
__device__ __forceinline__ float scatter_reduce16(float (&v)[16], int lane) {
    #pragma unroll
    for (int m = 32, nv = 16; m >= 4; m >>= 1, nv >>= 1) {
        const int half = nv >> 1;
        const bool hi = (lane & m) != 0;
        #pragma unroll
        for (int t = 0; t < 8; ++t) {
            if (t < half) {
                float send = hi ? v[t] : v[t + half];
                float recv = __shfl_xor(send, m, 64);
                v[t] = (hi ? v[t + half] : v[t]) + recv;
            }
        }
    }
    float r = v[0];
    r += __shfl_xor(r, 2, 64);
    r += __shfl_xor(r, 1, 64);
    return r;
}

// ---------------- Kernel 1: fused LN1 -> W1 -> ReLU -> LN2 -> W2 -> keys ---
__global__ __launch_bounds__(256) void k_scores(
    const float* __restrict__ table,
    const float* __restrict__ ln1_g, const float* __restrict__ ln1_b,
    const float* __restrict__ W1, const float* __restrict__ b1,
    const float* __restrict__ ln2_g, const float* __restrict__ ln2_b,
    const float* __restrict__ W2, const float* __restrict__ b2,
    u64* __restrict__ keys)
{
    const int lane = threadIdx.x & 63;
    const int gw = (blockIdx.x * blockDim.x + threadIdx.x) >> 6;
    const int nw = (gridDim.x * blockDim.x) >> 6;
    const int hsel = (lane >> 2) & 15;

    float w1g[4][16];
    float up[16], cp[16];
    #pragma unroll
    for (int h = 0; h < 16; ++h) { up[h] = 0.f; cp[h] = 0.f; }
    #pragma unroll
    for (int r = 0; r < 4; ++r) {
        const int f = 4*lane + r;
        const float g  = ln1_g[f];
        const float bb = ln1_b[f];
        #pragma unroll
        for (int q = 0; q < 4; ++q) {
            float4 w = *(const float4*)(W1 + f*16 + 4*q);
            float wv[4] = {w.x, w.y, w.z, w.w};
            #pragma unroll
            for (int j = 0; j < 4; ++j) {
                int h = 4*q + j;
                cp[h] += bb * wv[j];
                float wg = g * wv[j];
                w1g[r][h] = wg;
                up[h] += wg;
            }
        }
    }
    const float uph = scatter_reduce16(up, lane);
    const float cph = scatter_reduce16(cp, lane) + b1[hsel];

    float U2 = 0.f, C2 = b2[0];
    #pragma unroll
    for (int h = 0; h < 16; ++h) {
        float w2v = W2[h];
        U2 += ln2_g[h] * w2v;
        C2 += ln2_b[h] * w2v;
    }
    const float gwh = ln2_g[hsel] * W2[hsel];

    for (int row = gw; row < TOT; row += nw) {
        float4 x4 = *(const float4*)(table + (size_t)row*NF + 4*lane);
        float xs[4] = {x4.x, x4.y, x4.z, x4.w};
        float sum = 0.f, ssq = 0.f;
        float dx[16];
        #pragma unroll
        for (int h = 0; h < 16; ++h) dx[h] = 0.f;
        #pragma unroll
        for (int r = 0; r < 4; ++r) {
            sum += xs[r];
            ssq += xs[r]*xs[r];
            #pragma unroll
            for (int h = 0; h < 16; ++h) dx[h] += xs[r]*w1g[r][h];
        }
        #pragma unroll
        for (int m = 32; m >= 1; m >>= 1) {
            sum += __shfl_xor(sum, m, 64);
            ssq += __shfl_xor(ssq, m, 64);
        }
        const float dxh = scatter_reduce16(dx, lane);

        float mu   = sum * (1.f/NF);
        float var  = ssq * (1.f/NF) - mu*mu;
        float rstd = rsqrtf(var + 1e-5f);

        float hv = rstd * (dxh - mu*uph) + cph;
        hv = fmaxf(hv, 0.f);
        float s2 = hv, q2 = hv*hv, dh = hv*gwh;
        #pragma unroll
        for (int m = 4; m <= 32; m <<= 1) {
            s2 += __shfl_xor(s2, m, 64);
            q2 += __shfl_xor(q2, m, 64);
            dh += __shfl_xor(dh, m, 64);
        }
        float mu2   = s2 * (1.f/NH);
        float var2  = q2 * (1.f/NH) - mu2*mu2;
        float rstd2 = rsqrtf(var2 + 1e-5f);
        float sc = rstd2 * (dh - mu2*U2) + C2;
        if (lane == 0)
            keys[row] = ((u64)f2u(sc) << 32) | (u64)(row & (NR-1));
    }
}

// ---------------- Kernel 2: bitonic sort on u64 keys, descending ----------
// 2048-element chunks in LDS; 6 cross-chunk global passes.
__global__ __launch_bounds__(256) void k_sort_local_first(u64* __restrict__ keys) {
    __shared__ u64 sk[2048];
    const int base_g = blockIdx.x * 2048;
    for (int t = threadIdx.x; t < 2048; t += 256) sk[t] = keys[base_g + t];
    __syncthreads();
    for (int k = 2; k <= 2048; k <<= 1) {
        for (int j = k >> 1; j > 0; j >>= 1) {
            for (int t = threadIdx.x; t < 1024; t += 256) {
                int i = ((t & ~(j-1)) << 1) | (t & (j-1));
                int l = i | j;
                int gi = (base_g + i) & (NR - 1);
                bool dir = ((gi & k) == 0);
                u64 a = sk[i], b = sk[l];
                if ((b > a) == dir) { sk[i] = b; sk[l] = a; }
            }
            __syncthreads();
        }
    }
    for (int t = threadIdx.x; t < 2048; t += 256) keys[base_g + t] = sk[t];
}

__global__ __launch_bounds__(256) void k_sort_global(u64* __restrict__ keys, int k, int j) {
    int gt = blockIdx.x * 256 + threadIdx.x;     // TOT/2 pairs
    int b  = gt >> 13;                           // 8192 pairs per batch
    int t  = gt & 8191;
    int i  = ((t & ~(j-1)) << 1) | (t & (j-1));
    int l  = i | j;
    bool dir = ((i & k) == 0);
    u64* kb = keys + (size_t)b * NR;
    u64 a = kb[i], c = kb[l];
    if ((c > a) == dir) { kb[i] = c; kb[l] = a; }
}

__global__ __launch_bounds__(256) void k_sort_local(u64* __restrict__ keys, int K) {
    __shared__ u64 sk[2048];
    const int base_g = blockIdx.x * 2048;
    for (int t = threadIdx.x; t < 2048; t += 256) sk[t] = keys[base_g + t];
    __syncthreads();
    for (int j = 1024; j > 0; j >>= 1) {
        for (int t = threadIdx.x; t < 1024; t += 256) {
            int i = ((t & ~(j-1)) << 1) | (t & (j-1));
            int l = i | j;
            int gi = (base_g + i) & (NR - 1);
            bool dir = ((gi & K) == 0);
            u64 a = sk[i], b = sk[l];
            if ((b > a) == dir) { sk[i] = b; sk[l] = a; }
        }
        __syncthreads();
    }
    for (int t = threadIdx.x; t < 2048; t += 256) keys[base_g + t] = sk[t];
}

// ---------------- Kernel 3: isotonic via least-concave-majorant of cumsum ---
__global__ __launch_bounds__(1024) void k_pava(
    const u64* __restrict__ keys, const int* __restrict__ capp,
    int* __restrict__ Hbuf,
    float* __restrict__ out_soft, float* __restrict__ out_bins)
{
    __shared__ double S[NR];       // 128 KiB
    __shared__ double aux[2048];   // 16 KiB scan ping-pong
    __shared__ int cnt[1024];
    __shared__ int ti[512], tj[512], crA[512];

    const int b = blockIdx.x;
    const int tid = threadIdx.x;
    const u64* kb = keys + (size_t)b*NR;
    int* H = Hbuf + (size_t)b*NR;

    const float mx = u2f((unsigned)(kb[0] >> 32));
    const float mn = u2f((unsigned)(kb[NR-1] >> 32));
    const float scale = 10000.0f / (mx - mn);

    // 1) per-thread 16-element local scan of y = s_scaled - w (f64)
    double loc[16];
    double acc = 0.0;
    const int base = tid * 16;
    #pragma unroll
    for (int r = 0; r < 16; ++r) {
        int i = base + r;
        u64 key = kb[i];
        float s_i = (u2f((unsigned)(key >> 32)) - mn) * scale;
        double y = (double)s_i - (double)(NR - i);
        acc += y;
        loc[r] = acc;
    }
    aux[tid] = acc;
    __syncthreads();
    // 2) Hillis-Steele over 1024 thread totals
    int src = 0;
    for (int d = 1; d < 1024; d <<= 1) {
        double t = aux[src*1024 + tid];
        if (tid >= d) t += aux[src*1024 + tid - d];
        aux[(src^1)*1024 + tid] = t;
        src ^= 1;
        __syncthreads();
    }
    double excl = aux[src*1024 + tid] - acc;
    #pragma unroll
    for (int r = 0; r < 16; ++r) S[base + r] = excl + loc[r];
    __syncthreads();

    // cross(A,B,C) for hull points keyed by index k; y = S[k-1], S(0)=0
    #define SVAL(k) ((k) == 0 ? 0.0 : S[(k)-1])
    #define CRS(ka, kb_, kc) ( (double)((kb_)-(ka)) * (SVAL(kc) - SVAL(ka)) \
                             - (SVAL(kb_) - SVAL(ka)) * (double)((kc)-(ka)) )

    // 3) level-0: 16-point chunk upper hulls (one thread each)
    {
        int out = 0;
        #pragma unroll 1
        for (int r = 0; r < 16; ++r) {
            int k = base + r;
            while (out >= 2) {
                int kb2 = H[base + out - 1], ka = H[base + out - 2];
                if (CRS(ka, kb2, k) >= 0.0) --out;
                else break;
            }
            H[base + out++] = k;
        }
        cnt[tid] = out;
    }

    // 4) pairwise merges via upper tangent + parallel suffix copy
    for (int lev = 0; lev < 10; ++lev) {
        __syncthreads();
        const int pairs = 512 >> lev;
        const int Wd = 16 << lev;
        if (tid < pairs) {
            const int lbase = tid * 2 * Wd;
            const int rbase = lbase + Wd;
            int cl = cnt[(2*tid) << lev];
            int cr = cnt[(2*tid+1) << lev];
            int i = cl - 1, j = 0;
            bool moved = true;
            while (moved) {
                moved = false;
                while (i > 0) {
                    int ka = H[lbase+i-1], kb2 = H[lbase+i], kc = H[rbase+j];
                    if (CRS(ka, kb2, kc) >= 0.0) { --i; moved = true; }
                    else break;
                }
                while (j < cr - 1) {
                    int ka = H[lbase+i], kb2 = H[rbase+j], kc = H[rbase+j+1];
                    if (CRS(ka, kb2, kc) >= 0.0) { ++j; moved = true; }
                    else break;
                }
            }
            ti[tid] = i; tj[tid] = j; crA[tid] = cr;
            cnt[(2*tid) << lev] = (i + 1) + (cr - j);
        }
        __syncthreads();
        // parallel reg-staged copy of R[j..cr) to lbase+i+1
        const int tpp = 2 << lev;
        const int p = tid >> (1 + lev);
        const int q = tid & (tpp - 1);
        int vals[8];
        int len = 0, srcb = 0, dstb = 0;
        if (p < pairs) {
            const int lbase = p * 2 * Wd;
            const int rbase = lbase + Wd;
            const int i = ti[p], j = tj[p], cr = crA[p];
            len = cr - j;
            srcb = rbase + j;
            dstb = lbase + i + 1;
            #pragma unroll
            for (int t = 0; t < 8; ++t) {
                int e = q + t * tpp;
                if (e < len) vals[t] = H[srcb + e];
            }
        }
        __syncthreads();
        if (p < pairs) {
            #pragma unroll
            for (int t = 0; t < 8; ++t) {
                int e = q + t * tpp;
                if (e < len) H[dstb + e] = vals[t];
            }
        }
        __syncthreads();
    }

    // 5) append rightmost point k = NR
    if (tid == 0) {
        int out = cnt[0];
        while (out >= 2) {
            int kb2 = H[out - 1], ka = H[out - 2];
            if (CRS(ka, kb2, NR) >= 0.0) --out;
            else break;
        }
        H[out++] = NR;
        cnt[0] = out;
    }
    __syncthreads();

    // 6) slopes -> dual -> primal, scatter outputs; bins from hard rank
    const int m = cnt[0];
    const int cap = capp[0];
    for (int i = tid; i < NR; i += 1024) {
        int lo = 0, hi = m - 1;
        while (hi - lo > 1) {
            int mid = (lo + hi) >> 1;
            if (H[mid] <= i) lo = mid; else hi = mid;
        }
        int ka = H[lo], kb2 = H[hi];
        double slope = (SVAL(kb2) - SVAL(ka)) / (double)(kb2 - ka);
        u64 key = kb[i];
        float s_i = (u2f((unsigned)(key >> 32)) - mn) * scale;
        float primal = (float)((double)s_i - slope);
        int idx = (int)(key & 0xffffffffu);
        out_soft[(size_t)b*NR + idx] = primal;
        int rank = (NR - 1) - i;
        out_bins[(size_t)b*NR + idx] = (float)(rank / cap + 1);
    }
    #undef SVAL
    #undef CRS
}

extern "C" void kernel_launch(void* const* d_in, const int* in_sizes, int n_in,
                              void* d_out, int out_size, void* d_ws, size_t ws_size,
                              hipStream_t stream)
{
    const float* table = (const float*)d_in[0];
    const float* ln1_g = (const float*)d_in[1];
    const float* ln1_b = (const float*)d_in[2];
    const float* W1    = (const float*)d_in[3];
    const float* b1    = (const float*)d_in[4];
    const float* ln2_g = (const float*)d_in[5];
    const float* ln2_b = (const float*)d_in[6];
    const float* W2    = (const float*)d_in[7];
    const float* b2    = (const float*)d_in[8];
    const int*   cap   = (const int*)d_in[9];

    u64* keys = (u64*)d_ws;                 // TOT u64
    int* Hbuf = (int*)(keys + TOT);         // TOT i32

    float* out_soft = (float*)d_out;
    float* out_bins = ((float*)d_out) + TOT;

    k_scores<<<4096, 256, 0, stream>>>(table, ln1_g, ln1_b, W1, b1,
                                       ln2_g, ln2_b, W2, b2, keys);

    k_sort_local_first<<<TOT/2048, 256, 0, stream>>>(keys);
    k_sort_global<<<TOT/512, 256, 0, stream>>>(keys, 4096, 2048);
    k_sort_local <<<TOT/2048, 256, 0, stream>>>(keys, 4096);
    k_sort_global<<<TOT/512, 256, 0, stream>>>(keys, 8192, 4096);
    k_sort_global<<<TOT/512, 256, 0, stream>>>(keys, 8192, 2048);
    k_sort_local <<<TOT/2048, 256, 0, stream>>>(keys, 8192);
    k_sort_global<<<TOT/512, 256, 0, stream>>>(keys, 16384, 8192);
    k_sort_global<<<TOT/512, 256, 0, stream>>>(keys, 16384, 4096);
    k_sort_global<<<TOT/512, 256, 0, stream>>>(keys, 16384, 2048);
    k_sort_local <<<TOT/2048, 256, 0, stream>>>(keys, 16384);

    k_pava<<<NB, 1024, 0, stream>>>(keys, cap, Hbuf, out_soft, out_bins);
}

// Round 3
// 391.951 us; speedup vs baseline: 4.1569x; 2.9771x over previous
//
#include <hip/hip_runtime.h>

#define NB 32
#define NR 16384
#define NF 256
#define NH 16
#define TOT (NB*NR)
#define RPB 256      // rows per block in k_scores
#define KC 64        // K-chunk
#define LSTR 65      // LDS row stride (floats): bank = (row + k) % 32 -> 2-way (free)

typedef unsigned long long u64;

// float <-> order-preserving u32 (ascending uint == ascending float)
__device__ __forceinline__ unsigned int f2u(float f) {
    unsigned int u = __float_as_uint(f);
    return (u & 0x80000000u) ? ~u : (u | 0x80000000u);
}
__device__ __forceinline__ float u2f(unsigned int s) {
    unsigned int u = (s & 0x80000000u) ? (s ^ 0x80000000u) : ~s;
    return __uint_as_float(u);
}

// ---------------- Kernel 0: fold constants --------------------------------
// W1g[k][h] = ln1_g[k]*W1[k][h]
// consts: [0:16) cp[h] = sum_k ln1_b[k]*W1[k][h] + b1[h]
//         [16:32) up[h] = sum_k W1g[k][h]
//         [32:48) gw2[h] = ln2_g[h]*W2[h]
//         [48] U2 = sum gw2 ; [49] C2 = sum ln2_b[h]*W2[h] + b2
__global__ __launch_bounds__(256) void k_prep(
    const float* __restrict__ ln1_g, const float* __restrict__ ln1_b,
    const float* __restrict__ W1, const float* __restrict__ b1,
    const float* __restrict__ ln2_g, const float* __restrict__ ln2_b,
    const float* __restrict__ W2, const float* __restrict__ b2,
    float* __restrict__ W1g, float* __restrict__ consts)
{
    __shared__ float redc[16][16];
    __shared__ float redu[16][16];
    const int t = threadIdx.x;
    for (int e = t; e < NF*NH; e += 256) {
        int k = e >> 4;
        W1g[e] = ln1_g[k] * W1[e];
    }
    const int h = t & 15, kp = t >> 4;
    float pc = 0.f, pu = 0.f;
    #pragma unroll
    for (int r = 0; r < 16; ++r) {
        int k = kp*16 + r;
        float w = W1[k*NH + h];
        pc += ln1_b[k] * w;
        pu += ln1_g[k] * w;
    }
    redc[kp][h] = pc; redu[kp][h] = pu;
    __syncthreads();
    if (t < 16) {
        float sc = 0.f, su = 0.f;
        #pragma unroll
        for (int r = 0; r < 16; ++r) { sc += redc[r][t]; su += redu[r][t]; }
        consts[t]      = sc + b1[t];
        consts[16 + t] = su;
        consts[32 + t] = ln2_g[t] * W2[t];
    }
    if (t == 0) {
        float U2 = 0.f, C2 = b2[0];
        for (int hh = 0; hh < 16; ++hh) {
            U2 += ln2_g[hh] * W2[hh];
            C2 += ln2_b[hh] * W2[hh];
        }
        consts[48] = U2;
        consts[49] = C2;
    }
}

// ---------------- Kernel 1: thread-per-row fused scores -------------------
__global__ __launch_bounds__(256) void k_scores(
    const float* __restrict__ table,
    const float* __restrict__ W1g,
    const float* __restrict__ consts,
    u64* __restrict__ keys)
{
    __shared__ float xt[RPB * LSTR];   // 66,560 B
    const int t = threadIdx.x;
    const size_t rowBase = (size_t)blockIdx.x * RPB;

    float dx[16];
    #pragma unroll
    for (int h = 0; h < 16; ++h) dx[h] = 0.f;
    float sum = 0.f, ssq = 0.f;

    for (int c = 0; c < NF/KC; ++c) {
        // issue global loads EARLY (before barrier) — latency hides under
        // the other block's compute / previous chunk drain
        float4 v[16];
        #pragma unroll
        for (int p = 0; p < 16; ++p) {
            int q = p*256 + t;
            int r = q >> 4, cg = q & 15;
            v[p] = *(const float4*)(table + (rowBase + r)*NF + c*KC + cg*4);
        }
        __syncthreads();   // previous chunk's reads of xt are done
        #pragma unroll
        for (int p = 0; p < 16; ++p) {
            int q = p*256 + t;
            int r = q >> 4, cg = q & 15;
            float* dst = xt + r*LSTR + cg*4;
            dst[0] = v[p].x; dst[1] = v[p].y; dst[2] = v[p].z; dst[3] = v[p].w;
        }
        __syncthreads();

        const float4* __restrict__ Wg4 = (const float4*)W1g + (size_t)c*KC*4;
        const float*  __restrict__ xr  = xt + t*LSTR;
        #pragma unroll 4
        for (int k = 0; k < KC; ++k) {
            float x = xr[k];
            float4 w0 = Wg4[k*4+0];
            float4 w1 = Wg4[k*4+1];
            float4 w2 = Wg4[k*4+2];
            float4 w3 = Wg4[k*4+3];
            sum += x;
            ssq = fmaf(x, x, ssq);
            dx[ 0] = fmaf(x, w0.x, dx[ 0]);
            dx[ 1] = fmaf(x, w0.y, dx[ 1]);
            dx[ 2] = fmaf(x, w0.z, dx[ 2]);
            dx[ 3] = fmaf(x, w0.w, dx[ 3]);
            dx[ 4] = fmaf(x, w1.x, dx[ 4]);
            dx[ 5] = fmaf(x, w1.y, dx[ 5]);
            dx[ 6] = fmaf(x, w1.z, dx[ 6]);
            dx[ 7] = fmaf(x, w1.w, dx[ 7]);
            dx[ 8] = fmaf(x, w2.x, dx[ 8]);
            dx[ 9] = fmaf(x, w2.y, dx[ 9]);
            dx[10] = fmaf(x, w2.z, dx[10]);
            dx[11] = fmaf(x, w2.w, dx[11]);
            dx[12] = fmaf(x, w3.x, dx[12]);
            dx[13] = fmaf(x, w3.y, dx[13]);
            dx[14] = fmaf(x, w3.z, dx[14]);
            dx[15] = fmaf(x, w3.w, dx[15]);
        }
        if (c + 1 < NF/KC) __syncthreads();  // before overwriting xt
    }

    // epilogue: fully per-thread, no cross-lane ops
    const float mu   = sum * (1.f/NF);
    const float var  = ssq * (1.f/NF) - mu*mu;
    const float rstd = rsqrtf(var + 1e-5f);
    float s2 = 0.f, q2 = 0.f, dh = 0.f;
    #pragma unroll
    for (int h = 0; h < 16; ++h) {
        float hv = rstd * (dx[h] - mu * consts[16 + h]) + consts[h];
        hv = fmaxf(hv, 0.f);
        s2 += hv;
        q2 = fmaf(hv, hv, q2);
        dh = fmaf(hv, consts[32 + h], dh);
    }
    const float mu2   = s2 * (1.f/NH);
    const float var2  = q2 * (1.f/NH) - mu2*mu2;
    const float rstd2 = rsqrtf(var2 + 1e-5f);
    const float sc    = rstd2 * (dh - mu2 * consts[48]) + consts[49];

    const size_t row = rowBase + t;
    keys[row] = ((u64)f2u(sc) << 32) | (u64)(row & (NR-1));
}

// ---------------- Kernel 2: bitonic sort on u64 keys ----------------------
// 4096-element local chunks (1024 threads, 32 KiB LDS) + 3 global passes.
__global__ __launch_bounds__(1024) void k_sort_local_first(u64* __restrict__ keys) {
    __shared__ u64 sk[4096];
    const int base_g = blockIdx.x * 4096;
    for (int i = threadIdx.x; i < 4096; i += 1024) sk[i] = keys[base_g + i];
    __syncthreads();
    for (int k = 2; k <= 4096; k <<= 1) {
        for (int j = k >> 1; j > 0; j >>= 1) {
            for (int t = threadIdx.x; t < 2048; t += 1024) {
                int i = ((t & ~(j-1)) << 1) | (t & (j-1));
                int l = i | j;
                int gi = (base_g + i) & (NR - 1);
                bool dir = ((gi & k) == 0);
                u64 a = sk[i], b = sk[l];
                if ((b > a) == dir) { sk[i] = b; sk[l] = a; }
            }
            __syncthreads();
        }
    }
    for (int i = threadIdx.x; i < 4096; i += 1024) keys[base_g + i] = sk[i];
}

__global__ __launch_bounds__(256) void k_sort_global(u64* __restrict__ keys, int k, int j) {
    int gt = blockIdx.x * 256 + threadIdx.x;     // TOT/2 pairs
    int b  = gt >> 13;                           // 8192 pairs per batch
    int t  = gt & 8191;
    int i  = ((t & ~(j-1)) << 1) | (t & (j-1));
    int l  = i | j;
    bool dir = ((i & k) == 0);
    u64* kb = keys + (size_t)b * NR;
    u64 a = kb[i], c = kb[l];
    if ((c > a) == dir) { kb[i] = c; kb[l] = a; }
}

__global__ __launch_bounds__(1024) void k_sort_local_merge(u64* __restrict__ keys, int K) {
    __shared__ u64 sk[4096];
    const int base_g = blockIdx.x * 4096;
    for (int i = threadIdx.x; i < 4096; i += 1024) sk[i] = keys[base_g + i];
    __syncthreads();
    for (int j = 2048; j > 0; j >>= 1) {
        for (int t = threadIdx.x; t < 2048; t += 1024) {
            int i = ((t & ~(j-1)) << 1) | (t & (j-1));
            int l = i | j;
            int gi = (base_g + i) & (NR - 1);
            bool dir = ((gi & K) == 0);
            u64 a = sk[i], b = sk[l];
            if ((b > a) == dir) { sk[i] = b; sk[l] = a; }
        }
        __syncthreads();
    }
    for (int i = threadIdx.x; i < 4096; i += 1024) keys[base_g + i] = sk[i];
}

// ---------------- Kernel 3: isotonic via least-concave-majorant of cumsum ---
__global__ __launch_bounds__(1024) void k_pava(
    const u64* __restrict__ keys, const int* __restrict__ capp,
    int* __restrict__ Hbuf,
    float* __restrict__ out_soft, float* __restrict__ out_bins)
{
    __shared__ double S[NR];       // 128 KiB
    __shared__ double aux[2048];   // 16 KiB scan ping-pong
    __shared__ int cnt[1024];
    __shared__ int ti[512], tj[512], crA[512];

    const int b = blockIdx.x;
    const int tid = threadIdx.x;
    const u64* kb = keys + (size_t)b*NR;
    int* H = Hbuf + (size_t)b*NR;

    const float mx = u2f((unsigned)(kb[0] >> 32));
    const float mn = u2f((unsigned)(kb[NR-1] >> 32));
    const float scale = 10000.0f / (mx - mn);

    // 1) per-thread 16-element local scan of y = s_scaled - w (f64)
    double loc[16];
    double acc = 0.0;
    const int base = tid * 16;
    #pragma unroll
    for (int r = 0; r < 16; ++r) {
        int i = base + r;
        u64 key = kb[i];
        float s_i = (u2f((unsigned)(key >> 32)) - mn) * scale;
        double y = (double)s_i - (double)(NR - i);
        acc += y;
        loc[r] = acc;
    }
    aux[tid] = acc;
    __syncthreads();
    // 2) Hillis-Steele over 1024 thread totals
    int src = 0;
    for (int d = 1; d < 1024; d <<= 1) {
        double t = aux[src*1024 + tid];
        if (tid >= d) t += aux[src*1024 + tid - d];
        aux[(src^1)*1024 + tid] = t;
        src ^= 1;
        __syncthreads();
    }
    double excl = aux[src*1024 + tid] - acc;
    #pragma unroll
    for (int r = 0; r < 16; ++r) S[base + r] = excl + loc[r];
    __syncthreads();

    #define SVAL(k) ((k) == 0 ? 0.0 : S[(k)-1])
    #define CRS(ka, kb_, kc) ( (double)((kb_)-(ka)) * (SVAL(kc) - SVAL(ka)) \
                             - (SVAL(kb_) - SVAL(ka)) * (double)((kc)-(ka)) )

    // 3) level-0: 16-point chunk upper hulls (one thread each)
    {
        int out = 0;
        #pragma unroll 1
        for (int r = 0; r < 16; ++r) {
            int k = base + r;
            while (out >= 2) {
                int kb2 = H[base + out - 1], ka = H[base + out - 2];
                if (CRS(ka, kb2, k) >= 0.0) --out;
                else break;
            }
            H[base + out++] = k;
        }
        cnt[tid] = out;
    }

    // 4) pairwise merges via upper tangent + parallel suffix copy
    for (int lev = 0; lev < 10; ++lev) {
        __syncthreads();
        const int pairs = 512 >> lev;
        const int Wd = 16 << lev;
        if (tid < pairs) {
            const int lbase = tid * 2 * Wd;
            const int rbase = lbase + Wd;
            int cl = cnt[(2*tid) << lev];
            int cr = cnt[(2*tid+1) << lev];
            int i = cl - 1, j = 0;
            bool moved = true;
            while (moved) {
                moved = false;
                while (i > 0) {
                    int ka = H[lbase+i-1], kb2 = H[lbase+i], kc = H[rbase+j];
                    if (CRS(ka, kb2, kc) >= 0.0) { --i; moved = true; }
                    else break;
                }
                while (j < cr - 1) {
                    int ka = H[lbase+i], kb2 = H[rbase+j], kc = H[rbase+j+1];
                    if (CRS(ka, kb2, kc) >= 0.0) { ++j; moved = true; }
                    else break;
                }
            }
            ti[tid] = i; tj[tid] = j; crA[tid] = cr;
            cnt[(2*tid) << lev] = (i + 1) + (cr - j);
        }
        __syncthreads();
        // parallel reg-staged copy of R[j..cr) to lbase+i+1
        const int tpp = 2 << lev;
        const int p = tid >> (1 + lev);
        const int q = tid & (tpp - 1);
        int vals[8];
        int len = 0, srcb = 0, dstb = 0;
        if (p < pairs) {
            const int lbase = p * 2 * Wd;
            const int rbase = lbase + Wd;
            const int i = ti[p], j = tj[p], cr = crA[p];
            len = cr - j;
            srcb = rbase + j;
            dstb = lbase + i + 1;
            #pragma unroll
            for (int t = 0; t < 8; ++t) {
                int e = q + t * tpp;
                if (e < len) vals[t] = H[srcb + e];
            }
        }
        __syncthreads();
        if (p < pairs) {
            #pragma unroll
            for (int t = 0; t < 8; ++t) {
                int e = q + t * tpp;
                if (e < len) H[dstb + e] = vals[t];
            }
        }
        __syncthreads();
    }

    // 5) append rightmost point k = NR
    if (tid == 0) {
        int out = cnt[0];
        while (out >= 2) {
            int kb2 = H[out - 1], ka = H[out - 2];
            if (CRS(ka, kb2, NR) >= 0.0) --out;
            else break;
        }
        H[out++] = NR;
        cnt[0] = out;
    }
    __syncthreads();

    // 6) slopes -> dual -> primal, scatter outputs; bins from hard rank
    const int m = cnt[0];
    const int cap = capp[0];
    for (int i = tid; i < NR; i += 1024) {
        int lo = 0, hi = m - 1;
        while (hi - lo > 1) {
            int mid = (lo + hi) >> 1;
            if (H[mid] <= i) lo = mid; else hi = mid;
        }
        int ka = H[lo], kb2 = H[hi];
        double slope = (SVAL(kb2) - SVAL(ka)) / (double)(kb2 - ka);
        u64 key = kb[i];
        float s_i = (u2f((unsigned)(key >> 32)) - mn) * scale;
        float primal = (float)((double)s_i - slope);
        int idx = (int)(key & 0xffffffffu);
        out_soft[(size_t)b*NR + idx] = primal;
        int rank = (NR - 1) - i;
        out_bins[(size_t)b*NR + idx] = (float)(rank / cap + 1);
    }
    #undef SVAL
    #undef CRS
}

extern "C" void kernel_launch(void* const* d_in, const int* in_sizes, int n_in,
                              void* d_out, int out_size, void* d_ws, size_t ws_size,
                              hipStream_t stream)
{
    const float* table = (const float*)d_in[0];
    const float* ln1_g = (const float*)d_in[1];
    const float* ln1_b = (const float*)d_in[2];
    const float* W1    = (const float*)d_in[3];
    const float* b1    = (const float*)d_in[4];
    const float* ln2_g = (const float*)d_in[5];
    const float* ln2_b = (const float*)d_in[6];
    const float* W2    = (const float*)d_in[7];
    const float* b2    = (const float*)d_in[8];
    const int*   cap   = (const int*)d_in[9];

    u64*   keys   = (u64*)d_ws;                  // TOT u64  (4 MiB)
    int*   Hbuf   = (int*)(keys + TOT);          // TOT i32  (2 MiB)
    float* W1g    = (float*)(Hbuf + TOT);        // 4096 f32
    float* consts = W1g + NF*NH;                 // 64 f32

    float* out_soft = (float*)d_out;
    float* out_bins = ((float*)d_out) + TOT;

    k_prep<<<1, 256, 0, stream>>>(ln1_g, ln1_b, W1, b1, ln2_g, ln2_b, W2, b2,
                                  W1g, consts);
    k_scores<<<TOT/RPB, 256, 0, stream>>>(table, W1g, consts, keys);

    k_sort_local_first<<<TOT/4096, 1024, 0, stream>>>(keys);
    k_sort_global<<<TOT/512, 256, 0, stream>>>(keys, 8192, 4096);
    k_sort_local_merge<<<TOT/4096, 1024, 0, stream>>>(keys, 8192);
    k_sort_global<<<TOT/512, 256, 0, stream>>>(keys, 16384, 8192);
    k_sort_global<<<TOT/512, 256, 0, stream>>>(keys, 16384, 4096);
    k_sort_local_merge<<<TOT/4096, 1024, 0, stream>>>(keys, 16384);

    k_pava<<<NB, 1024, 0, stream>>>(keys, cap, Hbuf, out_soft, out_bins);
}